// Round 5
// baseline (3230.824 us; speedup 1.0000x reference)
//
#include <hip/hip_runtime.h>
#include <hip/hip_bf16.h>
#include <cstdint>
#include <cstddef>

typedef __attribute__((ext_vector_type(4))) float f32x4;
typedef __attribute__((ext_vector_type(8))) short s16x8;

#define D_ 128
#define H_ 512
#define CAT_ 384
#define BM 128
#define NPAN 12                         // 384 / 32
#define PPITCH 40                       // cat panel pitch (bf16): 32 + 8 pad
#define PH 520                          // h pitch (bf16): 512 + 8 pad
#define PAN_BYTES (BM * PPITCH * 2)     // 10240
#define H_BYTES (BM * PH * 2)           // 133120
#define LDS_BYTES (H_BYTES + 2 * PAN_BYTES)  // 153600 <= 160 KiB

__device__ __forceinline__ unsigned short f2bf(float x) {
  union { float f; unsigned u; } t; t.f = x;
  return (unsigned short)((t.u + 0x8000u) >> 16);
}

__device__ __forceinline__ float silu_f(float x) {
  return x / (1.0f + __expf(-x));
}

// Swapped-operand MFMA scheme: A = W-fragments (rows = weight output cols),
// B = activation fragments (cols = edges). D = h^T: lane&15 = edge,
// (lane>>4)*4 + r (+ m*16) = h column -> packed ushort4 stores, contiguous.
__global__ __launch_bounds__(1024, 4)
void edge_mlp_fused(const float* __restrict__ efeat,
                    const float* __restrict__ src_feat,
                    const float* __restrict__ dst_feat,
                    const int* __restrict__ src_idx,
                    const int* __restrict__ dst_idx,
                    const unsigned short* __restrict__ W1T,
                    const unsigned short* __restrict__ W2T,
                    const unsigned short* __restrict__ W3T,
                    const float* __restrict__ b1,
                    const float* __restrict__ b2,
                    const float* __restrict__ b3,
                    const float* __restrict__ gamma,
                    const float* __restrict__ beta,
                    float* __restrict__ out) {
  extern __shared__ char smem[];
  unsigned short* hbuf = (unsigned short*)smem;                 // h1 -> h2 (barrier-separated reuse)
  unsigned short* pan0 = (unsigned short*)(smem + H_BYTES);
  unsigned short* pan1 = pan0 + BM * PPITCH;

  const int tid = threadIdx.x;
  const int lane = tid & 63;
  const int wave = tid >> 6;            // 0..15
  const int nh = wave >> 3;             // col-half for GEMM1/2 (0..1)
  const int ne = wave & 7;              // edge 16-group (0..7)
  const int lr = lane & 15;             // A: wcol row sel / B,D: edge sel
  const int kh8 = (lane >> 4) * 8;      // k-offset within frag
  const int g4 = (lane >> 4) * 4;       // col-quad offset in C/D
  const size_t e0 = (size_t)blockIdx.x * BM;

  // gather mapping: 8 threads per row, one f32x4 each per 32-col panel
  const int grow = tid >> 3;            // 0..127
  const int gq = tid & 7;               // 0..7

  const int myedge = ne * 16 + lr;      // this lane's edge within block (B/D role)

  // ================= GEMM1: cat[128x384] (streamed panels) @ W1 -> silu -> h1 =================
  {
    const float* gbase[3];
    {
      const size_t e = e0 + grow;
      gbase[0] = efeat + e * D_;
      gbase[1] = src_feat + (size_t)src_idx[e] * D_;
      gbase[2] = dst_feat + (size_t)dst_idx[e] * D_;
    }
    f32x4 ga[2];

#define GLOAD(P, S) { ga[S] = *(const f32x4*)(gbase[(P) >> 2] + ((P) & 3) * 32 + gq * 4); }
#define PWRITE(P, S) { ushort4 w_; \
                       w_.x = f2bf(ga[S][0]); w_.y = f2bf(ga[S][1]); \
                       w_.z = f2bf(ga[S][2]); w_.w = f2bf(ga[S][3]); \
                       *(ushort4*)((((P) & 1) ? pan1 : pan0) + grow * PPITCH + gq * 4) = w_; }

    f32x4 acc[16];
    #pragma unroll
    for (int m = 0; m < 16; ++m) acc[m] = (f32x4){0.f, 0.f, 0.f, 0.f};

    const unsigned short* wbase = W1T + (size_t)(nh * 256 + lr) * CAT_ + kh8;

    GLOAD(0, 0); PWRITE(0, 0); GLOAD(1, 1);
    __syncthreads();

    #pragma unroll
    for (int p = 0; p < NPAN; ++p) {
      if (p + 1 < NPAN) {
        PWRITE(p + 1, (p + 1) & 1);
        if (p + 2 < NPAN) GLOAD(p + 2, p & 1);
      }
      const unsigned short* pb = (p & 1) ? pan1 : pan0;
      const s16x8 bf = *(const s16x8*)(pb + myedge * PPITCH + kh8);
      #pragma unroll
      for (int mq = 0; mq < 4; ++mq) {
        s16x8 w[4];
        #pragma unroll
        for (int j = 0; j < 4; ++j)
          w[j] = *(const s16x8*)(wbase + (size_t)(mq * 64 + j * 16) * CAT_ + p * 32);
        #pragma unroll
        for (int j = 0; j < 4; ++j)
          acc[mq * 4 + j] = __builtin_amdgcn_mfma_f32_16x16x32_bf16(w[j], bf, acc[mq * 4 + j], 0, 0, 0);
      }
      __syncthreads();
    }

    // silu + packed store -> h1 (contiguous 4 cols per lane)
    #pragma unroll
    for (int m = 0; m < 16; ++m) {
      const int colb = nh * 256 + m * 16 + g4;
      const f32x4 bv = *(const f32x4*)(b1 + colb);
      ushort4 w_;
      w_.x = f2bf(silu_f(acc[m][0] + bv[0]));
      w_.y = f2bf(silu_f(acc[m][1] + bv[1]));
      w_.z = f2bf(silu_f(acc[m][2] + bv[2]));
      w_.w = f2bf(silu_f(acc[m][3] + bv[3]));
      *(ushort4*)(hbuf + myedge * PH + colb) = w_;
    }
#undef GLOAD
#undef PWRITE
  }
  __syncthreads();   // h1 visible to all

  // ================= GEMM2: h1[128x512] @ W2 -> silu -> h2 (same buffer) =================
  {
    f32x4 acc[16];
    #pragma unroll
    for (int m = 0; m < 16; ++m) acc[m] = (f32x4){0.f, 0.f, 0.f, 0.f};

    const unsigned short* hrow = hbuf + myedge * PH + kh8;

    #pragma unroll
    for (int mq = 0; mq < 4; ++mq) {
      const unsigned short* w0 = W2T + (size_t)(nh * 256 + mq * 64 + lr) * H_ + kh8;
      const unsigned short* w1 = w0 + (size_t)16 * H_;
      const unsigned short* w2 = w0 + (size_t)32 * H_;
      const unsigned short* w3 = w0 + (size_t)48 * H_;
      #pragma unroll
      for (int kk = 0; kk < 16; ++kk) {
        const s16x8 bf = *(const s16x8*)(hrow + kk * 32);
        s16x8 wa = *(const s16x8*)(w0 + kk * 32);
        s16x8 wb = *(const s16x8*)(w1 + kk * 32);
        s16x8 wc = *(const s16x8*)(w2 + kk * 32);
        s16x8 wd = *(const s16x8*)(w3 + kk * 32);
        acc[mq * 4 + 0] = __builtin_amdgcn_mfma_f32_16x16x32_bf16(wa, bf, acc[mq * 4 + 0], 0, 0, 0);
        acc[mq * 4 + 1] = __builtin_amdgcn_mfma_f32_16x16x32_bf16(wb, bf, acc[mq * 4 + 1], 0, 0, 0);
        acc[mq * 4 + 2] = __builtin_amdgcn_mfma_f32_16x16x32_bf16(wc, bf, acc[mq * 4 + 2], 0, 0, 0);
        acc[mq * 4 + 3] = __builtin_amdgcn_mfma_f32_16x16x32_bf16(wd, bf, acc[mq * 4 + 3], 0, 0, 0);
      }
    }
    __syncthreads();   // all h1 reads complete before h2 overwrites

    #pragma unroll
    for (int m = 0; m < 16; ++m) {
      const int colb = nh * 256 + m * 16 + g4;
      const f32x4 bv = *(const f32x4*)(b2 + colb);
      ushort4 w_;
      w_.x = f2bf(silu_f(acc[m][0] + bv[0]));
      w_.y = f2bf(silu_f(acc[m][1] + bv[1]));
      w_.z = f2bf(silu_f(acc[m][2] + bv[2]));
      w_.w = f2bf(silu_f(acc[m][3] + bv[3]));
      *(ushort4*)(hbuf + myedge * PH + colb) = w_;
    }
  }
  __syncthreads();   // h2 visible

  // ===== GEMM3 (waves 0..7): h2[128x512] @ W3 + b3 -> y in regs -> LayerNorm -> out =====
  if (wave < 8) {
    f32x4 acc[8];
    #pragma unroll
    for (int m = 0; m < 8; ++m) acc[m] = (f32x4){0.f, 0.f, 0.f, 0.f};

    const unsigned short* hrow = hbuf + (wave * 16 + lr) * PH + kh8;

    #pragma unroll
    for (int mq = 0; mq < 2; ++mq) {
      const unsigned short* w0 = W3T + (size_t)(mq * 64 + lr) * H_ + kh8;
      const unsigned short* w1 = w0 + (size_t)16 * H_;
      const unsigned short* w2 = w0 + (size_t)32 * H_;
      const unsigned short* w3 = w0 + (size_t)48 * H_;
      #pragma unroll
      for (int kk = 0; kk < 16; ++kk) {
        const s16x8 bf = *(const s16x8*)(hrow + kk * 32);
        s16x8 wa = *(const s16x8*)(w0 + kk * 32);
        s16x8 wb = *(const s16x8*)(w1 + kk * 32);
        s16x8 wc = *(const s16x8*)(w2 + kk * 32);
        s16x8 wd = *(const s16x8*)(w3 + kk * 32);
        acc[mq * 4 + 0] = __builtin_amdgcn_mfma_f32_16x16x32_bf16(wa, bf, acc[mq * 4 + 0], 0, 0, 0);
        acc[mq * 4 + 1] = __builtin_amdgcn_mfma_f32_16x16x32_bf16(wb, bf, acc[mq * 4 + 1], 0, 0, 0);
        acc[mq * 4 + 2] = __builtin_amdgcn_mfma_f32_16x16x32_bf16(wc, bf, acc[mq * 4 + 2], 0, 0, 0);
        acc[mq * 4 + 3] = __builtin_amdgcn_mfma_f32_16x16x32_bf16(wd, bf, acc[mq * 4 + 3], 0, 0, 0);
      }
    }

    // bias + LayerNorm fully in registers (lane owns edge; 4 lanes x 32 cols)
    float sum = 0.f, ss = 0.f;
    #pragma unroll
    for (int m = 0; m < 8; ++m) {
      const f32x4 bv = *(const f32x4*)(b3 + m * 16 + g4);
      #pragma unroll
      for (int r = 0; r < 4; ++r) {
        acc[m][r] += bv[r];
        sum += acc[m][r];
        ss += acc[m][r] * acc[m][r];
      }
    }
    sum += __shfl_xor(sum, 16, 64); ss += __shfl_xor(ss, 16, 64);
    sum += __shfl_xor(sum, 32, 64); ss += __shfl_xor(ss, 32, 64);
    const float mu = sum * (1.0f / 128.0f);
    const float var = ss * (1.0f / 128.0f) - mu * mu;
    const float rstd = rsqrtf(var + 1e-5f);

    float* orow = out + (e0 + wave * 16 + lr) * D_;
    #pragma unroll
    for (int m = 0; m < 8; ++m) {
      const f32x4 gv = *(const f32x4*)(gamma + m * 16 + g4);
      const f32x4 btv = *(const f32x4*)(beta + m * 16 + g4);
      f32x4 o;
      #pragma unroll
      for (int r = 0; r < 4; ++r)
        o[r] = (acc[m][r] - mu) * rstd * gv[r] + btv[r];
      *(f32x4*)(orow + m * 16 + g4) = o;
    }
  }
}

// W [K][N] f32 -> Wt [N][K] bf16 (tiled transpose, coalesced both sides)
__global__ void prep_wt(const float* __restrict__ src, unsigned short* __restrict__ dst,
                        int K, int N) {
  __shared__ float tile[32][33];
  const int bk = blockIdx.x * 32, bn = blockIdx.y * 32;
  const int tx = threadIdx.x & 31, ty = threadIdx.x >> 5;
  #pragma unroll
  for (int i = ty; i < 32; i += 8)
    tile[i][tx] = src[(size_t)(bk + i) * N + bn + tx];
  __syncthreads();
  #pragma unroll
  for (int i = ty; i < 32; i += 8)
    dst[(size_t)(bn + i) * K + bk + tx] = f2bf(tile[tx][i]);
}

extern "C" void kernel_launch(void* const* d_in, const int* in_sizes, int n_in,
                              void* d_out, int out_size, void* d_ws, size_t ws_size,
                              hipStream_t stream) {
  const float* efeat    = (const float*)d_in[0];
  const float* src_feat = (const float*)d_in[1];
  const float* dst_feat = (const float*)d_in[2];
  const int*   src_idx  = (const int*)d_in[3];
  const int*   dst_idx  = (const int*)d_in[4];
  const float* W1 = (const float*)d_in[5];
  const float* b1 = (const float*)d_in[6];
  const float* W2 = (const float*)d_in[7];
  const float* b2 = (const float*)d_in[8];
  const float* W3 = (const float*)d_in[9];
  const float* b3 = (const float*)d_in[10];
  const float* gamma = (const float*)d_in[11];
  const float* beta  = (const float*)d_in[12];

  unsigned short* W1T = (unsigned short*)d_ws;          // [512][384]
  unsigned short* W2T = W1T + 512 * 384;                // [512][512]
  unsigned short* W3T = W2T + 512 * 512;                // [128][512]

  (void)hipFuncSetAttribute((const void*)edge_mlp_fused,
                            hipFuncAttributeMaxDynamicSharedMemorySize, LDS_BYTES);

  prep_wt<<<dim3(12, 16), 256, 0, stream>>>(W1, W1T, CAT_, H_);
  prep_wt<<<dim3(16, 16), 256, 0, stream>>>(W2, W2T, H_, H_);
  prep_wt<<<dim3(16, 4),  256, 0, stream>>>(W3, W3T, H_, D_);

  const int nblocks = 400000 / BM; // 3125, exact
  edge_mlp_fused<<<nblocks, 1024, LDS_BYTES, stream>>>(
      efeat, src_feat, dst_feat, src_idx, dst_idx,
      W1T, W2T, W3T, b1, b2, b3, gamma, beta, (float*)d_out);
}

// Round 6
// 769.193 us; speedup vs baseline: 4.2003x; 4.2003x over previous
//
#include <hip/hip_runtime.h>
#include <hip/hip_bf16.h>
#include <cstdint>
#include <cstddef>

typedef __attribute__((ext_vector_type(4))) float f32x4;
typedef __attribute__((ext_vector_type(8))) short s16x8;

#define E_ 400000
#define D_ 128
#define H_ 512
#define CAT_ 384
#define BM 96
#define NBLK 4167                  // ceil(400000/96), last block rem=64

// ---- LDS map (bytes). h: 96 rows x 512 bf16 = 1024B/row, XOR-swizzled.
#define W1PAN0   0                 // W1 K-panels (32KB each) live in h region during GEMM1
#define W1PAN1   32768
#define CATPAN0  65536             // cat K-panels: 96*40*2 = 7680B each
#define CATPAN1  (65536 + 7680)
#define TAIL     98304             // W2 panels 32KB x2 / W3 panels 8KB x2
#define LDS_TOTAL 163840           // exactly 160 KiB

__device__ __forceinline__ unsigned short f2bf(float x) {
  union { float f; unsigned u; } t; t.f = x;
  return (unsigned short)((t.u + 0x8000u) >> 16);
}
__device__ __forceinline__ float silu_f(float x) { return x / (1.0f + __expf(-x)); }

__device__ __forceinline__ void gload16(const void* g, void* l) {
  __builtin_amdgcn_global_load_lds(
      (const __attribute__((address_space(1))) unsigned int*)g,
      (__attribute__((address_space(3))) unsigned int*)l, 16, 0, 0);
}

// h access with XOR swizzle: rows stride 1024B would be 32-way bank conflict;
// byte ^= (row&7)<<4 spreads 16 lanes over 8x16B slots (2-way = free, m136).
#define HS(row, byteoff) (smem + (row) * 1024 + ((byteoff) ^ (((row) & 7) << 4)))

// Swapped-operand MFMA: A = W-frag (rows = out-cols), B = act-frag (cols = edges).
// D: lane&15 = edge, (lane>>4)*4 + r = out-col -> packed ushort4 h-stores,
// and GEMM3 leaves y fully in registers for an in-reg LayerNorm.
__global__ __launch_bounds__(512, 2)
void edge_mlp_fused(const float* __restrict__ efeat,
                    const float* __restrict__ src_feat,
                    const float* __restrict__ dst_feat,
                    const int* __restrict__ src_idx,
                    const int* __restrict__ dst_idx,
                    const unsigned short* __restrict__ P1,   // panel-packed bf16 weights
                    const unsigned short* __restrict__ P2,
                    const unsigned short* __restrict__ P3,
                    const float* __restrict__ b1,
                    const float* __restrict__ b2,
                    const float* __restrict__ b3,
                    const float* __restrict__ gamma,
                    const float* __restrict__ beta,
                    float* __restrict__ out) {
  extern __shared__ char smem[];
  const int tid = threadIdx.x;
  const int lane = tid & 63;
  const int wave = tid >> 6;            // 0..7
  const int lr = lane & 15;             // frag row (A: out-col, B: edge)
  const int kc = lane >> 4;             // k-chunk 0..3 (8 k's each)
  const int g4 = kc * 4;                // C/D col-quad offset
  const size_t e0 = (size_t)blockIdx.x * BM;
  const int rem = (int)((size_t)E_ - e0 < (size_t)BM ? (size_t)E_ - e0 : (size_t)BM);

  // gather mapping: 4 threads per edge-row, 8 f32 each per 32-col panel (tid<384)
  const int grow = tid >> 2, gq = tid & 3;
  const float* gb0 = nullptr; const float* gb1 = nullptr; const float* gb2 = nullptr;
  if (tid < 384) {
    const int gr = grow < rem ? grow : rem - 1;
    const size_t ee = e0 + gr;
    gb0 = efeat + ee * D_;
    gb1 = src_feat + (size_t)src_idx[ee] * D_;
    gb2 = dst_feat + (size_t)dst_idx[ee] * D_;
  }
  f32x4 ga[2][2];

#define CGLOAD(P, S) { const float* s_ = ((P) < 4 ? gb0 : (P) < 8 ? gb1 : gb2) + ((P) & 3) * 32 + gq * 8; \
                       ga[S][0] = *(const f32x4*)s_; ga[S][1] = *(const f32x4*)(s_ + 4); }
#define CPWRITE(P, S) { unsigned short* d_ = (unsigned short*)(smem + (((P) & 1) ? CATPAN1 : CATPAN0)) + grow * 40 + gq * 8; \
                        ushort4 w_; \
                        w_.x = f2bf(ga[S][0][0]); w_.y = f2bf(ga[S][0][1]); \
                        w_.z = f2bf(ga[S][0][2]); w_.w = f2bf(ga[S][0][3]); \
                        *(ushort4*)d_ = w_; \
                        w_.x = f2bf(ga[S][1][0]); w_.y = f2bf(ga[S][1][1]); \
                        w_.z = f2bf(ga[S][1][2]); w_.w = f2bf(ga[S][1][3]); \
                        *(ushort4*)(d_ + 4) = w_; }

// Stage one 512-col x 32-k W panel (32KB) : 4 global_load_lds dwordx4 per wave.
// Packed layout: elem off = p*16384 + kc*4096 + col*8 + ko  (LDS image order).
#define STAGE_W512(Ppack, p, bufbase) { \
    const unsigned short* s_ = (Ppack) + (size_t)(p) * 16384 + wave * 512 + lane * 8; \
    char* l_ = smem + (bufbase) + wave * 1024; \
    gload16(s_, l_); \
    gload16(s_ + 4096,  l_ + 8192); \
    gload16(s_ + 8192,  l_ + 16384); \
    gload16(s_ + 12288, l_ + 24576); }

// Stage one 128-col x 32-k W3 panel (8KB): 1 instr per wave.
#define STAGE_W128(p, bufbase) { \
    const unsigned short* s_ = P3 + (size_t)(p) * 4096 + (wave >> 1) * 1024 + (wave & 1) * 512 + lane * 8; \
    char* l_ = smem + (bufbase) + (wave >> 1) * 2048 + (wave & 1) * 1024; \
    gload16(s_, l_); }

  // ================= GEMM1: cat[96x384] @ W1 -> silu -> h1 =================
  {
    f32x4 acc[6][4];
    #pragma unroll
    for (int eg = 0; eg < 6; ++eg)
      #pragma unroll
      for (int j = 0; j < 4; ++j) acc[eg][j] = (f32x4){0.f, 0.f, 0.f, 0.f};

    if (tid < 384) { CGLOAD(0, 0); CPWRITE(0, 0); CGLOAD(1, 1); }
    STAGE_W512(P1, 0, W1PAN0);
    __syncthreads();

    #pragma unroll
    for (int p = 0; p < 12; ++p) {
      if (p + 1 < 12) {
        STAGE_W512(P1, p + 1, ((p + 1) & 1) ? W1PAN1 : W1PAN0);
        if (tid < 384) { CPWRITE(p + 1, (p + 1) & 1); if (p + 2 < 12) CGLOAD(p + 2, p & 1); }
      }
      const unsigned short* cp = (const unsigned short*)(smem + ((p & 1) ? CATPAN1 : CATPAN0));
      const char* wp = smem + ((p & 1) ? W1PAN1 : W1PAN0) + kc * 8192;
      s16x8 bf[6], a[4];
      #pragma unroll
      for (int eg = 0; eg < 6; ++eg)
        bf[eg] = *(const s16x8*)(cp + (eg * 16 + lr) * 40 + kc * 8);
      #pragma unroll
      for (int j = 0; j < 4; ++j)
        a[j] = *(const s16x8*)(wp + ((wave * 4 + j) * 16 + lr) * 16);
      #pragma unroll
      for (int j = 0; j < 4; ++j)
        #pragma unroll
        for (int eg = 0; eg < 6; ++eg)
          acc[eg][j] = __builtin_amdgcn_mfma_f32_16x16x32_bf16(a[j], bf[eg], acc[eg][j], 0, 0, 0);
      __syncthreads();
    }

    STAGE_W512(P2, 0, TAIL);   // prefetch W2 panel 0 under the silu stores
    #pragma unroll
    for (int eg = 0; eg < 6; ++eg) {
      const int edge = eg * 16 + lr;
      #pragma unroll
      for (int j = 0; j < 4; ++j) {
        const int col0 = (wave * 4 + j) * 16 + g4;
        const f32x4 bv = *(const f32x4*)(b1 + col0);
        ushort4 w_;
        w_.x = f2bf(silu_f(acc[eg][j][0] + bv[0]));
        w_.y = f2bf(silu_f(acc[eg][j][1] + bv[1]));
        w_.z = f2bf(silu_f(acc[eg][j][2] + bv[2]));
        w_.w = f2bf(silu_f(acc[eg][j][3] + bv[3]));
        *(ushort4*)HS(edge, col0 * 2) = w_;
      }
    }
  }
  __syncthreads();

  // ================= GEMM2: h1[96x512] @ W2 -> silu -> h2 (same h buffer) =================
  {
    f32x4 acc[6][4];
    #pragma unroll
    for (int eg = 0; eg < 6; ++eg)
      #pragma unroll
      for (int j = 0; j < 4; ++j) acc[eg][j] = (f32x4){0.f, 0.f, 0.f, 0.f};

    #pragma unroll 2
    for (int p = 0; p < 16; ++p) {
      if (p + 1 < 16) STAGE_W512(P2, p + 1, TAIL + ((p + 1) & 1) * 32768);
      const int kb = p * 64 + kc * 16;
      const char* wp = smem + TAIL + (p & 1) * 32768 + kc * 8192;
      s16x8 bf[6], a[4];
      #pragma unroll
      for (int eg = 0; eg < 6; ++eg)
        bf[eg] = *(const s16x8*)HS(eg * 16 + lr, kb);
      #pragma unroll
      for (int j = 0; j < 4; ++j)
        a[j] = *(const s16x8*)(wp + ((wave * 4 + j) * 16 + lr) * 16);
      #pragma unroll
      for (int j = 0; j < 4; ++j)
        #pragma unroll
        for (int eg = 0; eg < 6; ++eg)
          acc[eg][j] = __builtin_amdgcn_mfma_f32_16x16x32_bf16(a[j], bf[eg], acc[eg][j], 0, 0, 0);
      __syncthreads();
    }

    STAGE_W128(0, TAIL);       // prefetch W3 panel 0 under the silu stores
    #pragma unroll
    for (int eg = 0; eg < 6; ++eg) {
      const int edge = eg * 16 + lr;
      #pragma unroll
      for (int j = 0; j < 4; ++j) {
        const int col0 = (wave * 4 + j) * 16 + g4;
        const f32x4 bv = *(const f32x4*)(b2 + col0);
        ushort4 w_;
        w_.x = f2bf(silu_f(acc[eg][j][0] + bv[0]));
        w_.y = f2bf(silu_f(acc[eg][j][1] + bv[1]));
        w_.z = f2bf(silu_f(acc[eg][j][2] + bv[2]));
        w_.w = f2bf(silu_f(acc[eg][j][3] + bv[3]));
        *(ushort4*)HS(edge, col0 * 2) = w_;
      }
    }
  }
  __syncthreads();

  // ===== GEMM3: h2[96x512] @ W3 + b3 -> y in regs -> LayerNorm -> out =====
  // waves 0..5 each own one 16-edge group, all 128 out cols; waves 6,7 stage+barrier only.
  {
    f32x4 acc[8];
    #pragma unroll
    for (int f = 0; f < 8; ++f) acc[f] = (f32x4){0.f, 0.f, 0.f, 0.f};

    #pragma unroll 2
    for (int p = 0; p < 16; ++p) {
      if (p + 1 < 16) STAGE_W128(p + 1, TAIL + ((p + 1) & 1) * 8192);
      if (wave < 6) {
        const s16x8 bf = *(const s16x8*)HS(wave * 16 + lr, p * 64 + kc * 16);
        const char* wp = smem + TAIL + (p & 1) * 8192 + kc * 2048;
        #pragma unroll
        for (int f = 0; f < 8; ++f) {
          const s16x8 a = *(const s16x8*)(wp + (f * 16 + lr) * 16);
          acc[f] = __builtin_amdgcn_mfma_f32_16x16x32_bf16(a, bf, acc[f], 0, 0, 0);
        }
      }
      __syncthreads();
    }

    if (wave < 6) {
      const int edge = wave * 16 + lr;
      float sum = 0.f, ss = 0.f;
      #pragma unroll
      for (int f = 0; f < 8; ++f) {
        const f32x4 bv = *(const f32x4*)(b3 + f * 16 + g4);
        #pragma unroll
        for (int r = 0; r < 4; ++r) {
          acc[f][r] += bv[r];
          sum += acc[f][r];
          ss += acc[f][r] * acc[f][r];
        }
      }
      sum += __shfl_xor(sum, 16, 64); ss += __shfl_xor(ss, 16, 64);
      sum += __shfl_xor(sum, 32, 64); ss += __shfl_xor(ss, 32, 64);
      const float mu = sum * (1.0f / 128.0f);
      const float var = ss * (1.0f / 128.0f) - mu * mu;
      const float rstd = rsqrtf(var + 1e-5f);
      if (edge < rem) {
        float* orow = out + (e0 + edge) * D_;
        #pragma unroll
        for (int f = 0; f < 8; ++f) {
          const f32x4 gv = *(const f32x4*)(gamma + f * 16 + g4);
          const f32x4 btv = *(const f32x4*)(beta + f * 16 + g4);
          f32x4 o;
          #pragma unroll
          for (int r = 0; r < 4; ++r)
            o[r] = (acc[f][r] - mu) * rstd * gv[r] + btv[r];
          *(f32x4*)(orow + f * 16 + g4) = o;
        }
      }
    }
  }
#undef CGLOAD
#undef CPWRITE
#undef STAGE_W512
#undef STAGE_W128
}

// Pack W [K][N] f32 -> panel-packed bf16: elem off = p*(N*32) + kc*(N*8) + n*8 + ko
// (exactly the LDS panel image, so global_load_lds reads are fully contiguous).
__global__ void prep_pack(const float* __restrict__ W, unsigned short* __restrict__ P,
                          int K, int N) {
  const int t = blockIdx.x * blockDim.x + threadIdx.x;
  if (t >= N * (K >> 3)) return;
  const int n = t % N;
  const int k8 = t / N;
  const int k0 = k8 << 3;
  const int p = k0 >> 5, kc = (k0 >> 3) & 3;
  s16x8 w;
  #pragma unroll
  for (int j = 0; j < 8; ++j)
    w[j] = (short)f2bf(W[(size_t)(k0 + j) * N + n]);
  *(s16x8*)(P + (size_t)p * N * 32 + (size_t)kc * N * 8 + (size_t)n * 8) = w;
}

extern "C" void kernel_launch(void* const* d_in, const int* in_sizes, int n_in,
                              void* d_out, int out_size, void* d_ws, size_t ws_size,
                              hipStream_t stream) {
  const float* efeat    = (const float*)d_in[0];
  const float* src_feat = (const float*)d_in[1];
  const float* dst_feat = (const float*)d_in[2];
  const int*   src_idx  = (const int*)d_in[3];
  const int*   dst_idx  = (const int*)d_in[4];
  const float* W1 = (const float*)d_in[5];
  const float* b1 = (const float*)d_in[6];
  const float* W2 = (const float*)d_in[7];
  const float* b2 = (const float*)d_in[8];
  const float* W3 = (const float*)d_in[9];
  const float* b3 = (const float*)d_in[10];
  const float* gamma = (const float*)d_in[11];
  const float* beta  = (const float*)d_in[12];

  unsigned short* P1 = (unsigned short*)d_ws;           // 384*512  = 196608 elems
  unsigned short* P2 = P1 + 196608;                     // 512*512  = 262144
  unsigned short* P3 = P2 + 262144;                     // 512*128  = 65536

  (void)hipFuncSetAttribute((const void*)edge_mlp_fused,
                            hipFuncAttributeMaxDynamicSharedMemorySize, LDS_TOTAL);

  prep_pack<<<(512 * 48 + 255) / 256, 256, 0, stream>>>(W1, P1, CAT_, H_);
  prep_pack<<<(512 * 64 + 255) / 256, 256, 0, stream>>>(W2, P2, H_, H_);
  prep_pack<<<(128 * 64 + 255) / 256, 256, 0, stream>>>(W3, P3, H_, D_);

  edge_mlp_fused<<<NBLK, 512, LDS_TOTAL, stream>>>(
      efeat, src_feat, dst_feat, src_idx, dst_idx,
      P1, P2, P3, b1, b2, b3, gamma, beta, (float*)d_out);
}

// Round 7
// 603.179 us; speedup vs baseline: 5.3563x; 1.2752x over previous
//
#include <hip/hip_runtime.h>
#include <hip/hip_bf16.h>
#include <cstdint>
#include <cstddef>

typedef __attribute__((ext_vector_type(4))) float f32x4;
typedef __attribute__((ext_vector_type(8))) short s16x8;

#define E_ 400000
#define D_ 128
#define H_ 512
#define CAT_ 384
#define BM 96
#define NBLK 4167                       // ceil(400000/96), last rem=64

// LDS: h buffer 96 x 1024B (XOR-swizzled) at 0; cat ring-5 above.
#define CATPITCH 40                     // bf16 elems per cat row (32 + 8 pad)
#define CATSLOT (BM * CATPITCH * 2)     // 7680 B
#define CATBASE 98304                   // = 96*1024
#define LDS_TOTAL (CATBASE + 5 * CATSLOT)  // 136704 B <= 160 KiB

__device__ __forceinline__ unsigned short f2bf(float x) {
  union { float f; unsigned u; } t; t.f = x;
  return (unsigned short)((t.u + 0x8000u) >> 16);
}
__device__ __forceinline__ float silu_f(float x) {
  return x * __builtin_amdgcn_rcpf(1.0f + __expf(-x));
}

// h row stride 1024B would be 32-way bank conflict; XOR byte-bit spread -> free.
#define HS(row, byteoff) (smem + (row) * 1024 + ((byteoff) ^ (((row) & 7) << 4)))

// Swapped-operand MFMA: A = W frag (out-cols), B = activation frag (edges).
// D: lane&15 = edge, (lane>>4)*4 + r = out-col (16-col frag per j).
__global__ __launch_bounds__(512, 2)
void edge_mlp_fused(const float* __restrict__ efeat,
                    const float* __restrict__ src_feat,
                    const float* __restrict__ dst_feat,
                    const int* __restrict__ src_idx,
                    const int* __restrict__ dst_idx,
                    const unsigned short* __restrict__ P1,   // packed: p*16384 + kc*4096 + n*8
                    const unsigned short* __restrict__ P2,
                    const unsigned short* __restrict__ P3,   // p*4096 + kc*1024 + n*8
                    const float* __restrict__ b1,
                    const float* __restrict__ b2,
                    const float* __restrict__ b3,
                    const float* __restrict__ gamma,
                    const float* __restrict__ beta,
                    float* __restrict__ out) {
  extern __shared__ char smem[];
  const int tid = threadIdx.x;
  const int lane = tid & 63;
  const int wave = tid >> 6;            // 0..7
  const int lr = lane & 15;
  const int kc = lane >> 4;             // 0..3
  const int g4 = kc * 4;
  const size_t e0 = (size_t)blockIdx.x * BM;
  const int rem = (int)((size_t)E_ - e0 < (size_t)BM ? (size_t)E_ - e0 : (size_t)BM);

  // gather mapping: 4 threads per edge row, 8 floats each (tid < 384)
  const int grow = tid >> 2, gq = tid & 3;
  const float* gb0 = nullptr; const float* gb1 = nullptr; const float* gb2 = nullptr;
  if (tid < 384) {
    const int gr = grow < rem ? grow : rem - 1;
    const size_t ee = e0 + gr;
    gb0 = efeat + ee * D_;
    gb1 = src_feat + (size_t)src_idx[ee] * D_;
    gb2 = dst_feat + (size_t)dst_idx[ee] * D_;
  }
  f32x4 ga[2][2];

#define CGLOAD(P, S) { const float* s_ = ((P) < 4 ? gb0 : (P) < 8 ? gb1 : gb2) + ((P) & 3) * 32 + gq * 8; \
                       ga[S][0] = *(const f32x4*)s_; ga[S][1] = *(const f32x4*)(s_ + 4); }
#define CPWRITE(P, S) { unsigned short* d_ = (unsigned short*)(smem + CATBASE + ((P) % 5) * CATSLOT) + grow * CATPITCH + gq * 8; \
                        ushort4 w_; \
                        w_.x = f2bf(ga[S][0][0]); w_.y = f2bf(ga[S][0][1]); \
                        w_.z = f2bf(ga[S][0][2]); w_.w = f2bf(ga[S][0][3]); \
                        *(ushort4*)d_ = w_; \
                        w_.x = f2bf(ga[S][1][0]); w_.y = f2bf(ga[S][1][1]); \
                        w_.z = f2bf(ga[S][1][2]); w_.w = f2bf(ga[S][1][3]); \
                        *(ushort4*)(d_ + 4) = w_; }

  // per-wave W fragment base pointers (packed layout, frag = contiguous 16B)
  const unsigned short* w1base = P1 + (size_t)kc * 4096 + wave * 512 + lr * 8;
  const unsigned short* w2base = P2 + (size_t)kc * 4096 + wave * 512 + lr * 8;
  const unsigned short* w3base = P3 + (size_t)kc * 1024 + lr * 8;

  // ========== GEMM1: cat[96x384] (ring-5 streamed) @ W1 -> silu -> h1 ==========
  {
    f32x4 acc[6][4];
    #pragma unroll
    for (int eg = 0; eg < 6; ++eg)
      #pragma unroll
      for (int j = 0; j < 4; ++j) acc[eg][j] = (f32x4){0.f, 0.f, 0.f, 0.f};

    s16x8 w1r[2][4];
    if (tid < 384) {
      CGLOAD(0, 0); CPWRITE(0, 0);
      CGLOAD(1, 1); CPWRITE(1, 1);
      CGLOAD(2, 0); CPWRITE(2, 0);
      CGLOAD(3, 1);
    }
    #pragma unroll
    for (int j = 0; j < 4; ++j) w1r[0][j] = *(const s16x8*)(w1base + j * 128);

    asm volatile("s_waitcnt lgkmcnt(0)" ::: "memory");
    __builtin_amdgcn_s_barrier();
    asm volatile("" ::: "memory");

    #pragma unroll
    for (int p = 0; p < 12; ++p) {
      if (tid < 384) {
        if (p <= 8) CPWRITE(p + 3, (p + 1) & 1);   // uses CG(p+3) issued at step p-1
        if (p <= 7) CGLOAD(p + 4, p & 1);
      }
      if (p <= 10) {
        #pragma unroll
        for (int j = 0; j < 4; ++j)
          w1r[(p + 1) & 1][j] = *(const s16x8*)(w1base + (size_t)(p + 1) * 16384 + j * 128);
      }
      asm volatile("s_waitcnt lgkmcnt(0)" ::: "memory");   // publish cat writes
      __builtin_amdgcn_s_barrier();                         // raw barrier: NO vmcnt drain
      asm volatile("" ::: "memory");

      const unsigned short* cp = (const unsigned short*)(smem + CATBASE + (p % 5) * CATSLOT);
      s16x8 bf[6];
      #pragma unroll
      for (int eg = 0; eg < 6; ++eg)
        bf[eg] = *(const s16x8*)(cp + (eg * 16 + lr) * CATPITCH + kc * 8);
      #pragma unroll
      for (int j = 0; j < 4; ++j)
        #pragma unroll
        for (int eg = 0; eg < 6; ++eg)
          acc[eg][j] = __builtin_amdgcn_mfma_f32_16x16x32_bf16(w1r[p & 1][j], bf[eg], acc[eg][j], 0, 0, 0);
    }

    // silu -> h1 (h region untouched so far: no pre-barrier needed)
    #pragma unroll
    for (int j = 0; j < 4; ++j) {
      const int col0 = (wave * 4 + j) * 16 + g4;
      const f32x4 bv = *(const f32x4*)(b1 + col0);
      #pragma unroll
      for (int eg = 0; eg < 6; ++eg) {
        ushort4 w_;
        w_.x = f2bf(silu_f(acc[eg][j][0] + bv[0]));
        w_.y = f2bf(silu_f(acc[eg][j][1] + bv[1]));
        w_.z = f2bf(silu_f(acc[eg][j][2] + bv[2]));
        w_.w = f2bf(silu_f(acc[eg][j][3] + bv[3]));
        *(ushort4*)HS(eg * 16 + lr, col0 * 2) = w_;
      }
    }
  }
  __syncthreads();   // h1 visible

  // ========== GEMM2: h1[96x512] @ W2 -> silu -> h2 (barrier-free K-loop) ==========
  {
    f32x4 acc[6][4];
    #pragma unroll
    for (int eg = 0; eg < 6; ++eg)
      #pragma unroll
      for (int j = 0; j < 4; ++j) acc[eg][j] = (f32x4){0.f, 0.f, 0.f, 0.f};

    s16x8 w2r[2][4];
    #pragma unroll
    for (int j = 0; j < 4; ++j) w2r[0][j] = *(const s16x8*)(w2base + j * 128);

    #pragma unroll
    for (int p = 0; p < 16; ++p) {
      if (p <= 14) {
        #pragma unroll
        for (int j = 0; j < 4; ++j)
          w2r[(p + 1) & 1][j] = *(const s16x8*)(w2base + (size_t)(p + 1) * 16384 + j * 128);
      }
      s16x8 bf[6];
      #pragma unroll
      for (int eg = 0; eg < 6; ++eg)
        bf[eg] = *(const s16x8*)HS(eg * 16 + lr, p * 64 + kc * 16);
      #pragma unroll
      for (int j = 0; j < 4; ++j)
        #pragma unroll
        for (int eg = 0; eg < 6; ++eg)
          acc[eg][j] = __builtin_amdgcn_mfma_f32_16x16x32_bf16(w2r[p & 1][j], bf[eg], acc[eg][j], 0, 0, 0);
    }
    __syncthreads();   // all waves done READING h1 before overwrite

    #pragma unroll
    for (int j = 0; j < 4; ++j) {
      const int col0 = (wave * 4 + j) * 16 + g4;
      const f32x4 bv = *(const f32x4*)(b2 + col0);
      #pragma unroll
      for (int eg = 0; eg < 6; ++eg) {
        ushort4 w_;
        w_.x = f2bf(silu_f(acc[eg][j][0] + bv[0]));
        w_.y = f2bf(silu_f(acc[eg][j][1] + bv[1]));
        w_.z = f2bf(silu_f(acc[eg][j][2] + bv[2]));
        w_.w = f2bf(silu_f(acc[eg][j][3] + bv[3]));
        *(ushort4*)HS(eg * 16 + lr, col0 * 2) = w_;
      }
    }
  }
  __syncthreads();   // h2 visible

  // ===== GEMM3 (waves 0..5): h2 @ W3 + b3 -> y in regs -> LayerNorm -> out =====
  if (wave < 6) {
    f32x4 acc[8];
    #pragma unroll
    for (int f = 0; f < 8; ++f) acc[f] = (f32x4){0.f, 0.f, 0.f, 0.f};

    s16x8 w3r[2][8];
    #pragma unroll
    for (int f = 0; f < 8; ++f) w3r[0][f] = *(const s16x8*)(w3base + f * 128);

    #pragma unroll
    for (int p = 0; p < 16; ++p) {
      if (p <= 14) {
        #pragma unroll
        for (int f = 0; f < 8; ++f)
          w3r[(p + 1) & 1][f] = *(const s16x8*)(w3base + (size_t)(p + 1) * 4096 + f * 128);
      }
      const s16x8 bf = *(const s16x8*)HS(wave * 16 + lr, p * 64 + kc * 16);
      #pragma unroll
      for (int f = 0; f < 8; ++f)
        acc[f] = __builtin_amdgcn_mfma_f32_16x16x32_bf16(w3r[p & 1][f], bf, acc[f], 0, 0, 0);
    }

    const int edge = wave * 16 + lr;
    float sum = 0.f, ss = 0.f;
    #pragma unroll
    for (int f = 0; f < 8; ++f) {
      const f32x4 bv = *(const f32x4*)(b3 + f * 16 + g4);
      #pragma unroll
      for (int r = 0; r < 4; ++r) {
        acc[f][r] += bv[r];
        sum += acc[f][r];
        ss += acc[f][r] * acc[f][r];
      }
    }
    sum += __shfl_xor(sum, 16, 64); ss += __shfl_xor(ss, 16, 64);
    sum += __shfl_xor(sum, 32, 64); ss += __shfl_xor(ss, 32, 64);
    const float mu = sum * (1.0f / 128.0f);
    const float var = ss * (1.0f / 128.0f) - mu * mu;
    const float rstd = rsqrtf(var + 1e-5f);
    if (edge < rem) {
      float* orow = out + (e0 + edge) * D_;
      #pragma unroll
      for (int f = 0; f < 8; ++f) {
        const f32x4 gv = *(const f32x4*)(gamma + f * 16 + g4);
        const f32x4 btv = *(const f32x4*)(beta + f * 16 + g4);
        f32x4 o;
        #pragma unroll
        for (int r = 0; r < 4; ++r)
          o[r] = (acc[f][r] - mu) * rstd * gv[r] + btv[r];
        *(f32x4*)(orow + f * 16 + g4) = o;
      }
    }
  }
#undef CGLOAD
#undef CPWRITE
}

// Pack W [K][N] f32 -> bf16, elem off = p*(N*32) + kc*(N*8) + n*8 (frag-contiguous).
__global__ void prep_pack(const float* __restrict__ W, unsigned short* __restrict__ P,
                          int K, int N) {
  const int t = blockIdx.x * blockDim.x + threadIdx.x;
  if (t >= N * (K >> 3)) return;
  const int n = t % N;
  const int k8 = t / N;
  const int k0 = k8 << 3;
  const int p = k0 >> 5, kc = (k0 >> 3) & 3;
  s16x8 w;
  #pragma unroll
  for (int j = 0; j < 8; ++j)
    w[j] = (short)f2bf(W[(size_t)(k0 + j) * N + n]);
  *(s16x8*)(P + (size_t)p * N * 32 + (size_t)kc * N * 8 + (size_t)n * 8) = w;
}

extern "C" void kernel_launch(void* const* d_in, const int* in_sizes, int n_in,
                              void* d_out, int out_size, void* d_ws, size_t ws_size,
                              hipStream_t stream) {
  const float* efeat    = (const float*)d_in[0];
  const float* src_feat = (const float*)d_in[1];
  const float* dst_feat = (const float*)d_in[2];
  const int*   src_idx  = (const int*)d_in[3];
  const int*   dst_idx  = (const int*)d_in[4];
  const float* W1 = (const float*)d_in[5];
  const float* b1 = (const float*)d_in[6];
  const float* W2 = (const float*)d_in[7];
  const float* b2 = (const float*)d_in[8];
  const float* W3 = (const float*)d_in[9];
  const float* b3 = (const float*)d_in[10];
  const float* gamma = (const float*)d_in[11];
  const float* beta  = (const float*)d_in[12];

  unsigned short* P1 = (unsigned short*)d_ws;           // 196608 elems
  unsigned short* P2 = P1 + 196608;                     // 262144
  unsigned short* P3 = P2 + 262144;                     // 65536

  (void)hipFuncSetAttribute((const void*)edge_mlp_fused,
                            hipFuncAttributeMaxDynamicSharedMemorySize, LDS_TOTAL);

  prep_pack<<<(512 * 48 + 255) / 256, 256, 0, stream>>>(W1, P1, CAT_, H_);
  prep_pack<<<(512 * 64 + 255) / 256, 256, 0, stream>>>(W2, P2, H_, H_);
  prep_pack<<<(128 * 64 + 255) / 256, 256, 0, stream>>>(W3, P3, H_, D_);

  edge_mlp_fused<<<NBLK, 512, LDS_TOTAL, stream>>>(
      efeat, src_feat, dst_feat, src_idx, dst_idx,
      P1, P2, P3, b1, b2, b3, gamma, beta, (float*)d_out);
}

// Round 9
// 572.037 us; speedup vs baseline: 5.6479x; 1.0544x over previous
//
#include <hip/hip_runtime.h>
#include <hip/hip_bf16.h>
#include <cstdint>
#include <cstddef>

typedef __attribute__((ext_vector_type(4))) float f32x4;
typedef __attribute__((ext_vector_type(8))) short s16x8;

#define E_ 400000
#define D_ 128
#define H_ 512
#define CAT_ 384
#define BM 64
#define NBLK 6250                       // 400000/64 exact, no tail

// LDS: h buffer 64 x 1024B (XOR-swizzled) = 64 KiB total.
// cat ring-5 EMBEDDED in the top of the h region (h untouched until the
// post-barrier h1 stores, which happen after the last ring read).
// Ring-5 with write-distance 3: slot written at step p was last read at
// step p-2 -> separated by barrier_{p-1}. (Ring-4 raced: same-interval WAR.)
#define CATPITCH 40                     // bf16 elems per cat row (32 + 8 pad)
#define CATSLOT (BM * CATPITCH * 2)     // 5120 B
#define RINGBASE (65536 - 5 * CATSLOT)  // 39936 = h row 39
#define LDS_TOTAL 65536                 // 64 KiB -> 2 blocks/CU

__device__ __forceinline__ unsigned short f2bf(float x) {
  union { float f; unsigned u; } t; t.f = x;
  return (unsigned short)((t.u + 0x8000u) >> 16);
}
__device__ __forceinline__ float silu_f(float x) {
  return x * __builtin_amdgcn_rcpf(1.0f + __expf(-x));
}

// h row stride 1024B would be 32-way bank conflict; XOR spread -> ~2-way (free).
#define HS(row, byteoff) (smem + (row) * 1024 + ((byteoff) ^ (((row) & 7) << 4)))

// Swapped-operand MFMA: A = W frag (out-cols), B = activation frag (edges).
// D: lane&15 = edge, (lane>>4)*4 + r = out-col.
__global__ __launch_bounds__(512, 4)
void edge_mlp_fused(const float* __restrict__ efeat,
                    const float* __restrict__ src_feat,
                    const float* __restrict__ dst_feat,
                    const int* __restrict__ src_idx,
                    const int* __restrict__ dst_idx,
                    const unsigned short* __restrict__ P1,   // packed: p*16384 + kc*4096 + n*8
                    const unsigned short* __restrict__ P2,
                    const unsigned short* __restrict__ P3,   // p*4096 + kc*1024 + n*8
                    const float* __restrict__ b1,
                    const float* __restrict__ b2,
                    const float* __restrict__ b3,
                    const float* __restrict__ gamma,
                    const float* __restrict__ beta,
                    float* __restrict__ out) {
  extern __shared__ char smem[];
  const int tid = threadIdx.x;
  const int lane = tid & 63;
  const int wave = tid >> 6;            // 0..7
  const int lr = lane & 15;
  const int kc = lane >> 4;             // 0..3
  const int g4 = kc * 4;
  const size_t e0 = (size_t)blockIdx.x * BM;

  // gather mapping: 8 threads per edge row, one f32x4 per 32-col panel
  const int grow = tid >> 3, gq = tid & 7;
  const size_t ee = e0 + grow;
  const float* gb0 = efeat + ee * D_;
  const float* gb1 = src_feat + (size_t)src_idx[ee] * D_;
  const float* gb2 = dst_feat + (size_t)dst_idx[ee] * D_;
  f32x4 ga[2];

#define CGLOAD(P) { ga[(P) & 1] = *(const f32x4*)(((P) < 4 ? gb0 : (P) < 8 ? gb1 : gb2) + ((P) & 3) * 32 + gq * 4); }
#define CPWRITE(P) { unsigned short* d_ = (unsigned short*)(smem + RINGBASE + ((P) % 5) * CATSLOT) + grow * CATPITCH + gq * 4; \
                     const f32x4 v_ = ga[(P) & 1]; \
                     ushort4 w_; \
                     w_.x = f2bf(v_[0]); w_.y = f2bf(v_[1]); \
                     w_.z = f2bf(v_[2]); w_.w = f2bf(v_[3]); \
                     *(ushort4*)d_ = w_; }

  // per-wave W fragment base pointers (frag = contiguous 16B)
  const unsigned short* w1base = P1 + (size_t)kc * 4096 + wave * 512 + lr * 8;
  const unsigned short* w2base = P2 + (size_t)kc * 4096 + wave * 512 + lr * 8;
  const unsigned short* w3base = P3 + (size_t)kc * 1024 + lr * 8;

  // ========== GEMM1: cat[64x384] (ring-5 streamed) @ W1 -> silu -> h1 ==========
  {
    f32x4 acc[4][4];
    #pragma unroll
    for (int eg = 0; eg < 4; ++eg)
      #pragma unroll
      for (int j = 0; j < 4; ++j) acc[eg][j] = (f32x4){0.f, 0.f, 0.f, 0.f};

    CGLOAD(0); CPWRITE(0);
    CGLOAD(1); CPWRITE(1);
    CGLOAD(2); CPWRITE(2);
    CGLOAD(3);

    asm volatile("s_waitcnt lgkmcnt(0)" ::: "memory");
    __builtin_amdgcn_s_barrier();
    asm volatile("" ::: "memory");

    #pragma unroll
    for (int p = 0; p < 12; ++p) {
      // W loads for this step issued pre-barrier: latency spans the barrier.
      s16x8 w[4];
      #pragma unroll
      for (int j = 0; j < 4; ++j)
        w[j] = *(const s16x8*)(w1base + (size_t)p * 16384 + j * 128);

      if (p <= 8) { CPWRITE(p + 3); if (p <= 7) CGLOAD(p + 4); }

      asm volatile("s_waitcnt lgkmcnt(0)" ::: "memory");   // publish cat writes
      __builtin_amdgcn_s_barrier();                         // raw: no vmcnt drain
      asm volatile("" ::: "memory");

      const unsigned short* cp = (const unsigned short*)(smem + RINGBASE + (p % 5) * CATSLOT);
      #pragma unroll
      for (int eg = 0; eg < 4; ++eg) {
        const s16x8 bf = *(const s16x8*)(cp + (eg * 16 + lr) * CATPITCH + kc * 8);
        #pragma unroll
        for (int j = 0; j < 4; ++j)
          acc[eg][j] = __builtin_amdgcn_mfma_f32_16x16x32_bf16(w[j], bf, acc[eg][j], 0, 0, 0);
      }
    }

    // all ring reads done by every wave before h1 stores touch the ring area
    __builtin_amdgcn_s_barrier();
    asm volatile("" ::: "memory");

    #pragma unroll
    for (int j = 0; j < 4; ++j) {
      const int col0 = (wave * 4 + j) * 16 + g4;
      const f32x4 bv = *(const f32x4*)(b1 + col0);
      #pragma unroll
      for (int eg = 0; eg < 4; ++eg) {
        ushort4 w_;
        w_.x = f2bf(silu_f(acc[eg][j][0] + bv[0]));
        w_.y = f2bf(silu_f(acc[eg][j][1] + bv[1]));
        w_.z = f2bf(silu_f(acc[eg][j][2] + bv[2]));
        w_.w = f2bf(silu_f(acc[eg][j][3] + bv[3]));
        *(ushort4*)HS(eg * 16 + lr, col0 * 2) = w_;
      }
    }
  }
  __syncthreads();   // h1 visible

  // ========== GEMM2: h1[64x512] @ W2 -> silu -> h2 (barrier-free K-loop) ==========
  {
    f32x4 acc[4][4];
    #pragma unroll
    for (int eg = 0; eg < 4; ++eg)
      #pragma unroll
      for (int j = 0; j < 4; ++j) acc[eg][j] = (f32x4){0.f, 0.f, 0.f, 0.f};

    #pragma unroll
    for (int p = 0; p < 16; ++p) {
      s16x8 w[4];
      #pragma unroll
      for (int j = 0; j < 4; ++j)
        w[j] = *(const s16x8*)(w2base + (size_t)p * 16384 + j * 128);
      #pragma unroll
      for (int eg = 0; eg < 4; ++eg) {
        const s16x8 bf = *(const s16x8*)HS(eg * 16 + lr, p * 64 + kc * 16);
        #pragma unroll
        for (int j = 0; j < 4; ++j)
          acc[eg][j] = __builtin_amdgcn_mfma_f32_16x16x32_bf16(w[j], bf, acc[eg][j], 0, 0, 0);
      }
    }
    __syncthreads();   // all waves done READING h1 before overwrite

    #pragma unroll
    for (int j = 0; j < 4; ++j) {
      const int col0 = (wave * 4 + j) * 16 + g4;
      const f32x4 bv = *(const f32x4*)(b2 + col0);
      #pragma unroll
      for (int eg = 0; eg < 4; ++eg) {
        ushort4 w_;
        w_.x = f2bf(silu_f(acc[eg][j][0] + bv[0]));
        w_.y = f2bf(silu_f(acc[eg][j][1] + bv[1]));
        w_.z = f2bf(silu_f(acc[eg][j][2] + bv[2]));
        w_.w = f2bf(silu_f(acc[eg][j][3] + bv[3]));
        *(ushort4*)HS(eg * 16 + lr, col0 * 2) = w_;
      }
    }
  }
  __syncthreads();   // h2 visible

  // ===== GEMM3 (waves 0..3): h2 @ W3 + b3 -> y in regs -> LayerNorm -> out =====
  if (wave < 4) {
    f32x4 acc[8];
    #pragma unroll
    for (int f = 0; f < 8; ++f) acc[f] = (f32x4){0.f, 0.f, 0.f, 0.f};

    #pragma unroll
    for (int p = 0; p < 16; ++p) {
      s16x8 w[8];
      #pragma unroll
      for (int f = 0; f < 8; ++f)
        w[f] = *(const s16x8*)(w3base + (size_t)p * 4096 + f * 128);
      const s16x8 bf = *(const s16x8*)HS(wave * 16 + lr, p * 64 + kc * 16);
      #pragma unroll
      for (int f = 0; f < 8; ++f)
        acc[f] = __builtin_amdgcn_mfma_f32_16x16x32_bf16(w[f], bf, acc[f], 0, 0, 0);
    }

    const int edge = wave * 16 + lr;
    float sum = 0.f, ss = 0.f;
    #pragma unroll
    for (int f = 0; f < 8; ++f) {
      const f32x4 bv = *(const f32x4*)(b3 + f * 16 + g4);
      #pragma unroll
      for (int r = 0; r < 4; ++r) {
        acc[f][r] += bv[r];
        sum += acc[f][r];
        ss += acc[f][r] * acc[f][r];
      }
    }
    sum += __shfl_xor(sum, 16, 64); ss += __shfl_xor(ss, 16, 64);
    sum += __shfl_xor(sum, 32, 64); ss += __shfl_xor(ss, 32, 64);
    const float mu = sum * (1.0f / 128.0f);
    const float var = ss * (1.0f / 128.0f) - mu * mu;
    const float rstd = rsqrtf(var + 1e-5f);
    float* orow = out + (e0 + edge) * D_;
    #pragma unroll
    for (int f = 0; f < 8; ++f) {
      const f32x4 gv = *(const f32x4*)(gamma + f * 16 + g4);
      const f32x4 btv = *(const f32x4*)(beta + f * 16 + g4);
      f32x4 o;
      #pragma unroll
      for (int r = 0; r < 4; ++r)
        o[r] = (acc[f][r] - mu) * rstd * gv[r] + btv[r];
      *(f32x4*)(orow + f * 16 + g4) = o;
    }
  }
#undef CGLOAD
#undef CPWRITE
}

// Pack W [K][N] f32 -> bf16, elem off = p*(N*32) + kc*(N*8) + n*8 (frag-contiguous).
__global__ void prep_pack(const float* __restrict__ W, unsigned short* __restrict__ P,
                          int K, int N) {
  const int t = blockIdx.x * blockDim.x + threadIdx.x;
  if (t >= N * (K >> 3)) return;
  const int n = t % N;
  const int k8 = t / N;
  const int k0 = k8 << 3;
  const int p = k0 >> 5, kc = (k0 >> 3) & 3;
  s16x8 w;
  #pragma unroll
  for (int j = 0; j < 8; ++j)
    w[j] = (short)f2bf(W[(size_t)(k0 + j) * N + n]);
  *(s16x8*)(P + (size_t)p * N * 32 + (size_t)kc * N * 8 + (size_t)n * 8) = w;
}

extern "C" void kernel_launch(void* const* d_in, const int* in_sizes, int n_in,
                              void* d_out, int out_size, void* d_ws, size_t ws_size,
                              hipStream_t stream) {
  const float* efeat    = (const float*)d_in[0];
  const float* src_feat = (const float*)d_in[1];
  const float* dst_feat = (const float*)d_in[2];
  const int*   src_idx  = (const int*)d_in[3];
  const int*   dst_idx  = (const int*)d_in[4];
  const float* W1 = (const float*)d_in[5];
  const float* b1 = (const float*)d_in[6];
  const float* W2 = (const float*)d_in[7];
  const float* b2 = (const float*)d_in[8];
  const float* W3 = (const float*)d_in[9];
  const float* b3 = (const float*)d_in[10];
  const float* gamma = (const float*)d_in[11];
  const float* beta  = (const float*)d_in[12];

  unsigned short* P1 = (unsigned short*)d_ws;           // 196608 elems
  unsigned short* P2 = P1 + 196608;                     // 262144
  unsigned short* P3 = P2 + 262144;                     // 65536

  (void)hipFuncSetAttribute((const void*)edge_mlp_fused,
                            hipFuncAttributeMaxDynamicSharedMemorySize, LDS_TOTAL);

  prep_pack<<<(512 * 48 + 255) / 256, 256, 0, stream>>>(W1, P1, CAT_, H_);
  prep_pack<<<(512 * 64 + 255) / 256, 256, 0, stream>>>(W2, P2, H_, H_);
  prep_pack<<<(128 * 64 + 255) / 256, 256, 0, stream>>>(W3, P3, H_, D_);

  edge_mlp_fused<<<NBLK, 512, LDS_TOTAL, stream>>>(
      efeat, src_feat, dst_feat, src_idx, dst_idx,
      P1, P2, P3, b1, b2, b3, gamma, beta, (float*)d_out);
}